// Round 1
// baseline (567.955 us; speedup 1.0000x reference)
//
#include <hip/hip_runtime.h>
#include <math.h>

// TriangleAttention: B=1, I=J=384, C=128, H=4, D=32, fp32 in/out.
//
// prep:  transpose 5 weight mats (wq,wk,wv,wg,wo) to bf16 [n][k] B-frag layout;
//        Q_SCALE folded into wq.
// proj:  LN (fp32) + tri bias; xn -> bf16 swizzled LDS A-tile; 4 MFMA GEMMs
//        (16x16x32 bf16) -> q,k,v bf16 [i][h][j][d]; g sigmoid'ed -> bf16.
// attn:  MFMA flash attention per (i,h). Round-5 restructure: per-m-tile
//        P-write/PV interleave (Plds 52KB -> 17.4KB, occupancy 2 -> 4
//        blocks/CU) + single-barrier double-buffered K/V staging with
//        async issue-early/write-late split.
// out:   MFMA GEMM og[128 k = h*32+d] x woT -> out fp32 + bo.
//
// LDS swizzle (proj/out): row-major [row][128 bf16], 16 chunks of 8 bf16;
// chunk stored at (c ^ (row&7)). All hot phases <=2-way bank aliased.

#define I_DIM 384
#define J_DIM 384
#define C_DIM 128
#define H_DIM 4
#define D_DIM 32
#define NPOS (I_DIM * J_DIM)
#define Q_SCALE 0.17677669529663687f  // 1/sqrt(32)

typedef __attribute__((ext_vector_type(8))) short bf16x8;
typedef __attribute__((ext_vector_type(4))) float f32x4;

__device__ __forceinline__ float sigmoidf_(float v) {
    return 1.0f / (1.0f + __expf(-v));
}
__device__ __forceinline__ unsigned short f2bf(float f) {
    union { float f; unsigned u; } x; x.f = f;
    unsigned u = x.u;
    u += 0x7fffu + ((u >> 16) & 1u);
    return (unsigned short)(u >> 16);
}
__device__ __forceinline__ float bf2f(unsigned short v) {
    union { unsigned u; float f; } x; x.u = ((unsigned)v) << 16;
    return x.f;
}

// ---------------------------------------------------------------------------
// prep: Wt[mat][n][k] = W[k*128+n] (bf16), mat 0..4 = wq,wk,wv,wg,wo.
// ---------------------------------------------------------------------------
__global__ __launch_bounds__(256) void prep_kernel(
    const float* __restrict__ wq, const float* __restrict__ wk,
    const float* __restrict__ wv, const float* __restrict__ wg,
    const float* __restrict__ wo, unsigned short* __restrict__ Wt)
{
    const int mat = blockIdx.x;
    const float* W = (mat == 0) ? wq : (mat == 1) ? wk : (mat == 2) ? wv
                    : (mat == 3) ? wg : wo;
    const float scale = (mat == 0) ? Q_SCALE : 1.0f;
    const int t = threadIdx.x;
    const int n = t >> 1, c0 = (t & 1) * 64;
#pragma unroll
    for (int u = 0; u < 8; ++u) {
        unsigned pk[4];
#pragma unroll
        for (int w = 0; w < 4; ++w) {
            const unsigned short a = f2bf(W[(size_t)(c0 + u * 8 + w * 2 + 0) * 128 + n] * scale);
            const unsigned short b = f2bf(W[(size_t)(c0 + u * 8 + w * 2 + 1) * 128 + n] * scale);
            pk[w] = (unsigned)a | ((unsigned)b << 16);
        }
        int4 q; q.x = pk[0]; q.y = pk[1]; q.z = pk[2]; q.w = pk[3];
        *(int4*)(Wt + (size_t)mat * 16384 + n * 128 + c0 + u * 8) = q;
    }
}

// ---------------------------------------------------------------------------
// proj: grid = NPOS/128 = 1152, block = 256.  LDS 64KB -> 2 blocks/CU.
// ---------------------------------------------------------------------------
__global__ __launch_bounds__(256) void proj_kernel(
    const float* __restrict__ x, const float* __restrict__ ln_g,
    const float* __restrict__ ln_b, const float* __restrict__ w_tri,
    const unsigned short* __restrict__ Wt, const float* __restrict__ bg,
    unsigned short* __restrict__ qb, unsigned short* __restrict__ kb,
    unsigned short* __restrict__ vb, unsigned short* __restrict__ gb,
    float* __restrict__ tri)
{
    __shared__ unsigned short At[128 * 128];
    __shared__ unsigned short Bt[128 * 128];

    const int t = threadIdx.x;
    const int pos0 = blockIdx.x * 128;
    const int lane = t & 63, wave = t >> 6;
    const int q15 = lane & 15, quad = lane >> 4;

    // ---- LayerNorm + tri: thread (r = t>>1, half) owns 64 channels ----
    {
        const int r = t >> 1, half = t & 1, c0 = half * 64;
        const float* xrow = x + (size_t)(pos0 + r) * C_DIM + c0;
        float xv[64];
        float s = 0.f, ss = 0.f;
#pragma unroll
        for (int u = 0; u < 16; ++u) {
            float4 v4 = ((const float4*)xrow)[u];
            xv[u * 4 + 0] = v4.x; xv[u * 4 + 1] = v4.y;
            xv[u * 4 + 2] = v4.z; xv[u * 4 + 3] = v4.w;
            s  += v4.x + v4.y + v4.z + v4.w;
            ss += v4.x * v4.x + v4.y * v4.y + v4.z * v4.z + v4.w * v4.w;
        }
        s  += __shfl_xor(s, 1);
        ss += __shfl_xor(ss, 1);
        const float mu  = s * (1.0f / 128.0f);
        const float var = ss * (1.0f / 128.0f) - mu * mu;
        const float rstd = rsqrtf(var + 1e-5f);

        float ptri[4] = {0.f, 0.f, 0.f, 0.f};
#pragma unroll
        for (int u = 0; u < 8; ++u) {   // chunk of 8 channels
            const float4 g0 = ((const float4*)(ln_g + c0))[u * 2];
            const float4 g1 = ((const float4*)(ln_g + c0))[u * 2 + 1];
            const float4 b0 = ((const float4*)(ln_b + c0))[u * 2];
            const float4 b1 = ((const float4*)(ln_b + c0))[u * 2 + 1];
            float xn8[8];
            xn8[0] = (xv[u * 8 + 0] - mu) * rstd * g0.x + b0.x;
            xn8[1] = (xv[u * 8 + 1] - mu) * rstd * g0.y + b0.y;
            xn8[2] = (xv[u * 8 + 2] - mu) * rstd * g0.z + b0.z;
            xn8[3] = (xv[u * 8 + 3] - mu) * rstd * g0.w + b0.w;
            xn8[4] = (xv[u * 8 + 4] - mu) * rstd * g1.x + b1.x;
            xn8[5] = (xv[u * 8 + 5] - mu) * rstd * g1.y + b1.y;
            xn8[6] = (xv[u * 8 + 6] - mu) * rstd * g1.z + b1.z;
            xn8[7] = (xv[u * 8 + 7] - mu) * rstd * g1.w + b1.w;
#pragma unroll
            for (int w = 0; w < 8; ++w) {
                const float4 wt = ((const float4*)w_tri)[c0 + u * 8 + w];
                ptri[0] += xn8[w] * wt.x; ptri[1] += xn8[w] * wt.y;
                ptri[2] += xn8[w] * wt.z; ptri[3] += xn8[w] * wt.w;
            }
            unsigned pk[4];
#pragma unroll
            for (int w = 0; w < 4; ++w)
                pk[w] = (unsigned)f2bf(xn8[w * 2]) | ((unsigned)f2bf(xn8[w * 2 + 1]) << 16);
            int4 q4; q4.x = pk[0]; q4.y = pk[1]; q4.z = pk[2]; q4.w = pk[3];
            const int c = half * 8 + u;
            *(int4*)&At[r * 128 + ((c ^ (r & 7)) * 8)] = q4;
        }
#pragma unroll
        for (int hh = 0; hh < 4; ++hh) ptri[hh] += __shfl_xor(ptri[hh], 1);
        const int pos = pos0 + r;
        const int i = pos / J_DIM, j = pos - (pos / J_DIM) * J_DIM;
        const int h0 = half * 2;
        tri[((size_t)(h0 + 0) * J_DIM + j) * I_DIM + i] = ptri[h0 + 0];
        tri[((size_t)(h0 + 1) * J_DIM + j) * I_DIM + i] = ptri[h0 + 1];
    }

    const int m0 = wave * 32;
    for (int mat = 0; mat < 4; ++mat) {
        __syncthreads();
        // ---- stage B-tile (swizzled) ----
        {
            const int rn = t >> 1, half = t & 1;
            const unsigned short* src = Wt + (size_t)mat * 16384 + rn * 128 + half * 64;
#pragma unroll
            for (int u = 0; u < 8; ++u) {
                const int c = half * 8 + u;
                *(int4*)&Bt[rn * 128 + ((c ^ (rn & 7)) * 8)] = *(const int4*)(src + u * 8);
            }
        }
        __syncthreads();

        f32x4 acc[2][8];
#pragma unroll
        for (int mt = 0; mt < 2; ++mt)
#pragma unroll
            for (int nt = 0; nt < 8; ++nt) acc[mt][nt] = (f32x4){0.f, 0.f, 0.f, 0.f};

#pragma unroll
        for (int kk = 0; kk < 4; ++kk) {
            // all hot rows are ≡ q15 (mod 16) -> row&7 == q15&7 -> common swizzle
            const int sw = ((kk * 4 + quad) ^ (q15 & 7)) * 8;
            const bf16x8 a0 = *(const bf16x8*)&At[(m0 + q15) * 128 + sw];
            const bf16x8 a1 = *(const bf16x8*)&At[(m0 + 16 + q15) * 128 + sw];
#pragma unroll
            for (int nt = 0; nt < 8; ++nt) {
                const bf16x8 b = *(const bf16x8*)&Bt[(nt * 16 + q15) * 128 + sw];
                acc[0][nt] = __builtin_amdgcn_mfma_f32_16x16x32_bf16(a0, b, acc[0][nt], 0, 0, 0);
                acc[1][nt] = __builtin_amdgcn_mfma_f32_16x16x32_bf16(a1, b, acc[1][nt], 0, 0, 0);
            }
        }

        // ---- epilogue: C -> Bt (bf16, swizzled) -> vectorized global ----
        __syncthreads();
#pragma unroll
        for (int mt = 0; mt < 2; ++mt)
#pragma unroll
            for (int nt = 0; nt < 8; ++nt) {
                const int col = nt * 16 + q15;
                const float bgl = (mat == 3) ? bg[col] : 0.f;
#pragma unroll
                for (int reg = 0; reg < 4; ++reg) {
                    float v = acc[mt][nt][reg];
                    if (mat == 3) v = sigmoidf_(v + bgl);
                    const int row = m0 + mt * 16 + quad * 4 + reg;
                    Bt[row * 128 + (((col >> 3) ^ (row & 7)) * 8) + (col & 7)] = f2bf(v);
                }
            }
        __syncthreads();
        {
            unsigned short* O = (mat == 0) ? qb : (mat == 1) ? kb : (mat == 2) ? vb : gb;
#pragma unroll
            for (int sgm = 0; sgm < 2; ++sgm) {
                const int ch = t + sgm * 256;       // 512 chunks = 128 rows x 4 heads
                const int r = ch >> 2, hh = ch & 3;
                const int pos = pos0 + r;
                const int i = pos / J_DIM, j = pos - (pos / J_DIM) * J_DIM;
                unsigned short* dst = O + (((size_t)i * H_DIM + hh) * J_DIM + j) * D_DIM;
#pragma unroll
                for (int w = 0; w < 4; ++w) {
                    const int c = hh * 4 + w;
                    *(int4*)(dst + w * 8) = *(const int4*)&Bt[r * 128 + ((c ^ (r & 7)) * 8)];
                }
            }
        }
    }
}

// ---------------------------------------------------------------------------
// attn: MFMA flash attention.  grid = I*H = 1536, block = 256 (4 waves).
// Round-5: per-m-tile P interleave (Plds 16x68 x2 buffers per wave) +
// double-buffered K/V with async issue-early/write-late staging.
// LDS = 8K (K) + 8.5K (Vt) + 17.4K (P) + 1.5K (Mb) = 35.4KB -> 4 blocks/CU.
// ---------------------------------------------------------------------------
__global__ __launch_bounds__(256) void attn_kernel(
    const unsigned short* __restrict__ qb, const unsigned short* __restrict__ kb,
    const unsigned short* __restrict__ vb, unsigned short* gob,
    const float* __restrict__ triT, const float* __restrict__ mask)
{
    __shared__ unsigned short Klds[2][64 * 32];
    __shared__ unsigned short Vt[2][32 * 68];
    __shared__ unsigned short Plds[4][2][16 * 68];
    __shared__ float Mb[J_DIM];

    const int t = threadIdx.x;
    const int lane = t & 63, wave = t >> 6;
    const int q15 = lane & 15, quad = lane >> 4;
    const int i = blockIdx.x >> 2, h = blockIdx.x & 3;
    const size_t hb = (size_t)(i * H_DIM + h) * (J_DIM * D_DIM);
    const int m0 = wave * 96;

    for (int idx = t; idx < J_DIM; idx += 256)
        Mb[idx] = 1.0e9f * (mask[i * J_DIM + idx] - 1.0f);

    bf16x8 qf[6];
#pragma unroll
    for (int m = 0; m < 6; ++m)
        qf[m] = *(const bf16x8*)(qb + hb + (size_t)(m0 + m * 16 + q15) * D_DIM + quad * 8);

    f32x4 Oacc[6][2];
    float sums[6][4];
#pragma unroll
    for (int m = 0; m < 6; ++m) {
#pragma unroll
        for (int d2 = 0; d2 < 2; ++d2) Oacc[m][d2] = (f32x4){0.f, 0.f, 0.f, 0.f};
#pragma unroll
        for (int r = 0; r < 4; ++r) sums[m][r] = 0.f;
    }

    const float* triH = triT + (size_t)h * J_DIM * I_DIM;

    // staging geometry: 256 threads cover 64 rows x 32 d (16B per thread each of K,V)
    const int kp = t >> 2, du = (t & 3) * 8;
    int4 kreg, vreg;
    {   // prologue: stage kt=0 into buffer 0
        const size_t gsrc = hb + (size_t)kp * D_DIM + du;
        kreg = *(const int4*)(kb + gsrc);
        vreg = *(const int4*)(vb + gsrc);
        *(int4*)&Klds[0][kp * 32 + du] = kreg;
        const unsigned short* vs = (const unsigned short*)&vreg;
#pragma unroll
        for (int u = 0; u < 8; ++u)
            Vt[0][(du + u) * 68 + kp] = vs[u];
    }
    __syncthreads();

    for (int kt = 0; kt < 6; ++kt) {
        const int cur = kt & 1;

        // issue next tile's global loads early (latency hides under compute)
        if (kt < 5) {
            const size_t gsrc = hb + (size_t)((kt + 1) * 64 + kp) * D_DIM + du;
            kreg = *(const int4*)(kb + gsrc);
            vreg = *(const int4*)(vb + gsrc);
        }

        bf16x8 vf[2][2];
#pragma unroll
        for (int ks = 0; ks < 2; ++ks)
#pragma unroll
            for (int d2 = 0; d2 < 2; ++d2)
                vf[ks][d2] = *(const bf16x8*)&Vt[cur][(d2 * 16 + q15) * 68 + ks * 32 + quad * 8];

        float mbv[4];
#pragma unroll
        for (int nt = 0; nt < 4; ++nt)
            mbv[nt] = Mb[kt * 64 + nt * 16 + q15];

#pragma unroll
        for (int m = 0; m < 6; ++m) {
            unsigned short* Pw = &Plds[wave][m & 1][0];
#pragma unroll
            for (int nt = 0; nt < 4; ++nt) {
                const bf16x8 kf = *(const bf16x8*)&Klds[cur][(nt * 16 + q15) * 32 + quad * 8];
                const float* tcol = triH + (size_t)(kt * 64 + nt * 16 + q15) * I_DIM;
                const float4 tb = *(const float4*)(tcol + m0 + m * 16 + quad * 4);
                f32x4 s = {0.f, 0.f, 0.f, 0.f};
                s = __builtin_amdgcn_mfma_f32_16x16x32_bf16(qf[m], kf, s, 0, 0, 0);
                const float mb = mbv[nt];
                const float p0 = __expf(s[0] + mb + tb.x);
                const float p1 = __expf(s[1] + mb + tb.y);
                const float p2 = __expf(s[2] + mb + tb.z);
                const float p3 = __expf(s[3] + mb + tb.w);
                sums[m][0] += p0; sums[m][1] += p1;
                sums[m][2] += p2; sums[m][3] += p3;
                const int row = quad * 4;
                const int col = nt * 16 + q15;
                Pw[(row + 0) * 68 + col] = f2bf(p0);
                Pw[(row + 1) * 68 + col] = f2bf(p1);
                Pw[(row + 2) * 68 + col] = f2bf(p2);
                Pw[(row + 3) * 68 + col] = f2bf(p3);
            }
#pragma unroll
            for (int ks = 0; ks < 2; ++ks) {
                const bf16x8 af = *(const bf16x8*)&Pw[q15 * 68 + ks * 32 + quad * 8];
                Oacc[m][0] = __builtin_amdgcn_mfma_f32_16x16x32_bf16(af, vf[ks][0], Oacc[m][0], 0, 0, 0);
                Oacc[m][1] = __builtin_amdgcn_mfma_f32_16x16x32_bf16(af, vf[ks][1], Oacc[m][1], 0, 0, 0);
            }
        }

        // write next tile into the other buffer; one barrier per iteration.
        // Safe: buf[cur^1] was last READ in iteration kt-1, and the barrier at
        // the end of kt-1 ordered those reads before these writes.
        if (kt < 5) {
            *(int4*)&Klds[cur ^ 1][kp * 32 + du] = kreg;
            const unsigned short* vs = (const unsigned short*)&vreg;
#pragma unroll
            for (int u = 0; u < 8; ++u)
                Vt[cur ^ 1][(du + u) * 68 + kp] = vs[u];
            __syncthreads();
        }
    }

    float inv[6][4];
#pragma unroll
    for (int m = 0; m < 6; ++m)
#pragma unroll
        for (int r = 0; r < 4; ++r) {
            float s0 = sums[m][r];
            s0 += __shfl_xor(s0, 1); s0 += __shfl_xor(s0, 2);
            s0 += __shfl_xor(s0, 4); s0 += __shfl_xor(s0, 8);
            inv[m][r] = 1.0f / s0;
        }

#pragma unroll
    for (int m = 0; m < 6; ++m) {
        const int qrow = m0 + m * 16 + quad * 4;
#pragma unroll
        for (int d2 = 0; d2 < 2; ++d2) {
            const int d = d2 * 16 + q15;
#pragma unroll
            for (int r = 0; r < 4; ++r) {
                const size_t idx = hb + (size_t)(qrow + r) * D_DIM + d;
                const float g = bf2f(gob[idx]);
                gob[idx] = f2bf(Oacc[m][d2][r] * inv[m][r] * g);
            }
        }
    }
}

// ---------------------------------------------------------------------------
// out: MFMA GEMM.  grid = NPOS/128 = 1152, block = 256.
// ---------------------------------------------------------------------------
__global__ __launch_bounds__(256) void out_kernel(
    const unsigned short* __restrict__ og, const unsigned short* __restrict__ WtO,
    const float* __restrict__ bo, float* __restrict__ out)
{
    __shared__ unsigned short At[128 * 128];
    __shared__ unsigned short Bt[128 * 128];

    const int t = threadIdx.x;
    const int pos0 = blockIdx.x * 128;
    const int lane = t & 63, wave = t >> 6;
    const int q15 = lane & 15, quad = lane >> 4;

    {
        const int r = t >> 1, half = t & 1;
        const int pos = pos0 + r;
        const int i = pos / J_DIM, j = pos - (pos / J_DIM) * J_DIM;
#pragma unroll
        for (int u = 0; u < 8; ++u) {
            const int k0 = half * 64 + u * 8;
            const int hh = k0 >> 5, d0 = k0 & 31;
            const int4 v = *(const int4*)(og + (((size_t)i * H_DIM + hh) * J_DIM + j) * D_DIM + d0);
            const int c = half * 8 + u;
            *(int4*)&At[r * 128 + ((c ^ (r & 7)) * 8)] = v;
        }
        const unsigned short* src = WtO + r * 128 + half * 64;
#pragma unroll
        for (int u = 0; u < 8; ++u) {
            const int c = half * 8 + u;
            *(int4*)&Bt[r * 128 + ((c ^ (r & 7)) * 8)] = *(const int4*)(src + u * 8);
        }
    }
    __syncthreads();

    const int m0 = wave * 32;
    f32x4 acc[2][8];
#pragma unroll
    for (int mt = 0; mt < 2; ++mt)
#pragma unroll
        for (int nt = 0; nt < 8; ++nt) acc[mt][nt] = (f32x4){0.f, 0.f, 0.f, 0.f};

#pragma unroll
    for (int kk = 0; kk < 4; ++kk) {
        const int sw = ((kk * 4 + quad) ^ (q15 & 7)) * 8;
        const bf16x8 a0 = *(const bf16x8*)&At[(m0 + q15) * 128 + sw];
        const bf16x8 a1 = *(const bf16x8*)&At[(m0 + 16 + q15) * 128 + sw];
#pragma unroll
        for (int nt = 0; nt < 8; ++nt) {
            const bf16x8 b = *(const bf16x8*)&Bt[(nt * 16 + q15) * 128 + sw];
            acc[0][nt] = __builtin_amdgcn_mfma_f32_16x16x32_bf16(a0, b, acc[0][nt], 0, 0, 0);
            acc[1][nt] = __builtin_amdgcn_mfma_f32_16x16x32_bf16(a1, b, acc[1][nt], 0, 0, 0);
        }
    }

#pragma unroll
    for (int mt = 0; mt < 2; ++mt)
#pragma unroll
        for (int nt = 0; nt < 8; ++nt) {
            const float bov = bo[nt * 16 + q15];
#pragma unroll
            for (int reg = 0; reg < 4; ++reg) {
                const int pos = pos0 + m0 + mt * 16 + quad * 4 + reg;
                out[(size_t)pos * C_DIM + nt * 16 + q15] = acc[mt][nt][reg] + bov;
            }
        }
}

// ---------------------------------------------------------------------------
extern "C" void kernel_launch(void* const* d_in, const int* in_sizes, int n_in,
                              void* d_out, int out_size, void* d_ws, size_t ws_size,
                              hipStream_t stream)
{
    const float* x     = (const float*)d_in[0];
    const float* mask  = (const float*)d_in[1];
    const float* ln_g  = (const float*)d_in[2];
    const float* ln_b  = (const float*)d_in[3];
    const float* w_tri = (const float*)d_in[4];
    const float* wq    = (const float*)d_in[5];
    const float* wk    = (const float*)d_in[6];
    const float* wv    = (const float*)d_in[7];
    const float* wg    = (const float*)d_in[8];
    const float* bg    = (const float*)d_in[9];
    const float* wo    = (const float*)d_in[10];
    const float* bo    = (const float*)d_in[11];
    float* out = (float*)d_out;
    char* ws = (char*)d_ws;

    const size_t NE = (size_t)NPOS * 128;   // elements per [I,H,J,D] buffer
    unsigned short* qb = (unsigned short*)ws;                     // bf16 36 MiB
    unsigned short* kb = (unsigned short*)(ws + NE * 2);
    unsigned short* vb = (unsigned short*)(ws + NE * 4);
    unsigned short* gb = (unsigned short*)(ws + NE * 6);          // g -> og
    float*         tri = (float*)(ws + NE * 8);                   // [H][J][I]
    unsigned short* Wt = (unsigned short*)(ws + NE * 8 + (size_t)NPOS * 4 * 4);

    prep_kernel<<<5, 256, 0, stream>>>(wq, wk, wv, wg, wo, Wt);
    proj_kernel<<<NPOS / 128, 256, 0, stream>>>(x, ln_g, ln_b, w_tri, Wt, bg,
                                                qb, kb, vb, gb, tri);
    attn_kernel<<<I_DIM * H_DIM, 256, 0, stream>>>(qb, kb, vb, gb, tri, mask);
    out_kernel<<<NPOS / 128, 256, 0, stream>>>(gb, Wt + 4 * 16384, bo, out);
}

// Round 2
// 493.753 us; speedup vs baseline: 1.1503x; 1.1503x over previous
//
#include <hip/hip_runtime.h>
#include <math.h>

// TriangleAttention: B=1, I=J=384, C=128, H=4, D=32, fp32 in/out.
//
// prep:  transpose 5 weight mats (wq,wk,wv,wg,wo) to bf16 [n][k] B-frag layout;
//        Q_SCALE folded into wq.
// proj:  LN (fp32) + tri bias; xn -> bf16 swizzled LDS A-tile; 4 MFMA GEMMs
//        (16x16x32 bf16) -> q,k,v bf16 [i][h][j][d]; g sigmoid'ed -> bf16.
// attn:  MFMA flash attention per (i,h). Round-6: round-0 structure (nt-outer
//        QK^T, kf loaded once per nt) but each kt tile processed in 3 passes
//        of 2 m-tiles -> P scratch 96->32 rows/wave. LDS 62.5KB -> 27.4KB
//        -> 5 blocks/CU (was 2). No held-register staging (VGPR stays ~96).
// out:   MFMA GEMM og[128 k = h*32+d] x woT -> out fp32 + bo.
//
// LDS swizzle (proj/out): row-major [row][128 bf16], 16 chunks of 8 bf16;
// chunk stored at (c ^ (row&7)). All hot phases <=2-way bank aliased.

#define I_DIM 384
#define J_DIM 384
#define C_DIM 128
#define H_DIM 4
#define D_DIM 32
#define NPOS (I_DIM * J_DIM)
#define Q_SCALE 0.17677669529663687f  // 1/sqrt(32)

typedef __attribute__((ext_vector_type(8))) short bf16x8;
typedef __attribute__((ext_vector_type(4))) float f32x4;

__device__ __forceinline__ float sigmoidf_(float v) {
    return 1.0f / (1.0f + __expf(-v));
}
__device__ __forceinline__ unsigned short f2bf(float f) {
    union { float f; unsigned u; } x; x.f = f;
    unsigned u = x.u;
    u += 0x7fffu + ((u >> 16) & 1u);
    return (unsigned short)(u >> 16);
}
__device__ __forceinline__ float bf2f(unsigned short v) {
    union { unsigned u; float f; } x; x.u = ((unsigned)v) << 16;
    return x.f;
}

// ---------------------------------------------------------------------------
// prep: Wt[mat][n][k] = W[k*128+n] (bf16), mat 0..4 = wq,wk,wv,wg,wo.
// ---------------------------------------------------------------------------
__global__ __launch_bounds__(256) void prep_kernel(
    const float* __restrict__ wq, const float* __restrict__ wk,
    const float* __restrict__ wv, const float* __restrict__ wg,
    const float* __restrict__ wo, unsigned short* __restrict__ Wt)
{
    const int mat = blockIdx.x;
    const float* W = (mat == 0) ? wq : (mat == 1) ? wk : (mat == 2) ? wv
                    : (mat == 3) ? wg : wo;
    const float scale = (mat == 0) ? Q_SCALE : 1.0f;
    const int t = threadIdx.x;
    const int n = t >> 1, c0 = (t & 1) * 64;
#pragma unroll
    for (int u = 0; u < 8; ++u) {
        unsigned pk[4];
#pragma unroll
        for (int w = 0; w < 4; ++w) {
            const unsigned short a = f2bf(W[(size_t)(c0 + u * 8 + w * 2 + 0) * 128 + n] * scale);
            const unsigned short b = f2bf(W[(size_t)(c0 + u * 8 + w * 2 + 1) * 128 + n] * scale);
            pk[w] = (unsigned)a | ((unsigned)b << 16);
        }
        int4 q; q.x = pk[0]; q.y = pk[1]; q.z = pk[2]; q.w = pk[3];
        *(int4*)(Wt + (size_t)mat * 16384 + n * 128 + c0 + u * 8) = q;
    }
}

// ---------------------------------------------------------------------------
// proj: grid = NPOS/128 = 1152, block = 256.  LDS 64KB -> 2 blocks/CU.
// ---------------------------------------------------------------------------
__global__ __launch_bounds__(256) void proj_kernel(
    const float* __restrict__ x, const float* __restrict__ ln_g,
    const float* __restrict__ ln_b, const float* __restrict__ w_tri,
    const unsigned short* __restrict__ Wt, const float* __restrict__ bg,
    unsigned short* __restrict__ qb, unsigned short* __restrict__ kb,
    unsigned short* __restrict__ vb, unsigned short* __restrict__ gb,
    float* __restrict__ tri)
{
    __shared__ unsigned short At[128 * 128];
    __shared__ unsigned short Bt[128 * 128];

    const int t = threadIdx.x;
    const int pos0 = blockIdx.x * 128;
    const int lane = t & 63, wave = t >> 6;
    const int q15 = lane & 15, quad = lane >> 4;

    // ---- LayerNorm + tri: thread (r = t>>1, half) owns 64 channels ----
    {
        const int r = t >> 1, half = t & 1, c0 = half * 64;
        const float* xrow = x + (size_t)(pos0 + r) * C_DIM + c0;
        float xv[64];
        float s = 0.f, ss = 0.f;
#pragma unroll
        for (int u = 0; u < 16; ++u) {
            float4 v4 = ((const float4*)xrow)[u];
            xv[u * 4 + 0] = v4.x; xv[u * 4 + 1] = v4.y;
            xv[u * 4 + 2] = v4.z; xv[u * 4 + 3] = v4.w;
            s  += v4.x + v4.y + v4.z + v4.w;
            ss += v4.x * v4.x + v4.y * v4.y + v4.z * v4.z + v4.w * v4.w;
        }
        s  += __shfl_xor(s, 1);
        ss += __shfl_xor(ss, 1);
        const float mu  = s * (1.0f / 128.0f);
        const float var = ss * (1.0f / 128.0f) - mu * mu;
        const float rstd = rsqrtf(var + 1e-5f);

        float ptri[4] = {0.f, 0.f, 0.f, 0.f};
#pragma unroll
        for (int u = 0; u < 8; ++u) {   // chunk of 8 channels
            const float4 g0 = ((const float4*)(ln_g + c0))[u * 2];
            const float4 g1 = ((const float4*)(ln_g + c0))[u * 2 + 1];
            const float4 b0 = ((const float4*)(ln_b + c0))[u * 2];
            const float4 b1 = ((const float4*)(ln_b + c0))[u * 2 + 1];
            float xn8[8];
            xn8[0] = (xv[u * 8 + 0] - mu) * rstd * g0.x + b0.x;
            xn8[1] = (xv[u * 8 + 1] - mu) * rstd * g0.y + b0.y;
            xn8[2] = (xv[u * 8 + 2] - mu) * rstd * g0.z + b0.z;
            xn8[3] = (xv[u * 8 + 3] - mu) * rstd * g0.w + b0.w;
            xn8[4] = (xv[u * 8 + 4] - mu) * rstd * g1.x + b1.x;
            xn8[5] = (xv[u * 8 + 5] - mu) * rstd * g1.y + b1.y;
            xn8[6] = (xv[u * 8 + 6] - mu) * rstd * g1.z + b1.z;
            xn8[7] = (xv[u * 8 + 7] - mu) * rstd * g1.w + b1.w;
#pragma unroll
            for (int w = 0; w < 8; ++w) {
                const float4 wt = ((const float4*)w_tri)[c0 + u * 8 + w];
                ptri[0] += xn8[w] * wt.x; ptri[1] += xn8[w] * wt.y;
                ptri[2] += xn8[w] * wt.z; ptri[3] += xn8[w] * wt.w;
            }
            unsigned pk[4];
#pragma unroll
            for (int w = 0; w < 4; ++w)
                pk[w] = (unsigned)f2bf(xn8[w * 2]) | ((unsigned)f2bf(xn8[w * 2 + 1]) << 16);
            int4 q4; q4.x = pk[0]; q4.y = pk[1]; q4.z = pk[2]; q4.w = pk[3];
            const int c = half * 8 + u;
            *(int4*)&At[r * 128 + ((c ^ (r & 7)) * 8)] = q4;
        }
#pragma unroll
        for (int hh = 0; hh < 4; ++hh) ptri[hh] += __shfl_xor(ptri[hh], 1);
        const int pos = pos0 + r;
        const int i = pos / J_DIM, j = pos - (pos / J_DIM) * J_DIM;
        const int h0 = half * 2;
        tri[((size_t)(h0 + 0) * J_DIM + j) * I_DIM + i] = ptri[h0 + 0];
        tri[((size_t)(h0 + 1) * J_DIM + j) * I_DIM + i] = ptri[h0 + 1];
    }

    const int m0 = wave * 32;
    for (int mat = 0; mat < 4; ++mat) {
        __syncthreads();
        // ---- stage B-tile (swizzled) ----
        {
            const int rn = t >> 1, half = t & 1;
            const unsigned short* src = Wt + (size_t)mat * 16384 + rn * 128 + half * 64;
#pragma unroll
            for (int u = 0; u < 8; ++u) {
                const int c = half * 8 + u;
                *(int4*)&Bt[rn * 128 + ((c ^ (rn & 7)) * 8)] = *(const int4*)(src + u * 8);
            }
        }
        __syncthreads();

        f32x4 acc[2][8];
#pragma unroll
        for (int mt = 0; mt < 2; ++mt)
#pragma unroll
            for (int nt = 0; nt < 8; ++nt) acc[mt][nt] = (f32x4){0.f, 0.f, 0.f, 0.f};

#pragma unroll
        for (int kk = 0; kk < 4; ++kk) {
            // all hot rows are ≡ q15 (mod 16) -> row&7 == q15&7 -> common swizzle
            const int sw = ((kk * 4 + quad) ^ (q15 & 7)) * 8;
            const bf16x8 a0 = *(const bf16x8*)&At[(m0 + q15) * 128 + sw];
            const bf16x8 a1 = *(const bf16x8*)&At[(m0 + 16 + q15) * 128 + sw];
#pragma unroll
            for (int nt = 0; nt < 8; ++nt) {
                const bf16x8 b = *(const bf16x8*)&Bt[(nt * 16 + q15) * 128 + sw];
                acc[0][nt] = __builtin_amdgcn_mfma_f32_16x16x32_bf16(a0, b, acc[0][nt], 0, 0, 0);
                acc[1][nt] = __builtin_amdgcn_mfma_f32_16x16x32_bf16(a1, b, acc[1][nt], 0, 0, 0);
            }
        }

        // ---- epilogue: C -> Bt (bf16, swizzled) -> vectorized global ----
        __syncthreads();
#pragma unroll
        for (int mt = 0; mt < 2; ++mt)
#pragma unroll
            for (int nt = 0; nt < 8; ++nt) {
                const int col = nt * 16 + q15;
                const float bgl = (mat == 3) ? bg[col] : 0.f;
#pragma unroll
                for (int reg = 0; reg < 4; ++reg) {
                    float v = acc[mt][nt][reg];
                    if (mat == 3) v = sigmoidf_(v + bgl);
                    const int row = m0 + mt * 16 + quad * 4 + reg;
                    Bt[row * 128 + (((col >> 3) ^ (row & 7)) * 8) + (col & 7)] = f2bf(v);
                }
            }
        __syncthreads();
        {
            unsigned short* O = (mat == 0) ? qb : (mat == 1) ? kb : (mat == 2) ? vb : gb;
#pragma unroll
            for (int sgm = 0; sgm < 2; ++sgm) {
                const int ch = t + sgm * 256;       // 512 chunks = 128 rows x 4 heads
                const int r = ch >> 2, hh = ch & 3;
                const int pos = pos0 + r;
                const int i = pos / J_DIM, j = pos - (pos / J_DIM) * J_DIM;
                unsigned short* dst = O + (((size_t)i * H_DIM + hh) * J_DIM + j) * D_DIM;
#pragma unroll
                for (int w = 0; w < 4; ++w) {
                    const int c = hh * 4 + w;
                    *(int4*)(dst + w * 8) = *(const int4*)&Bt[r * 128 + ((c ^ (r & 7)) * 8)];
                }
            }
        }
    }
}

// ---------------------------------------------------------------------------
// attn: MFMA flash attention.  grid = I*H = 1536, block = 256 (4 waves).
// Round-0 inner structure; each kt processed as 3 passes x 2 m-tiles so the
// per-wave P scratch is 32x68 (17.4KB total) instead of 96x68 (52KB).
// LDS = 4K (K) + 4.3K (Vt) + 17.4K (P) + 1.5K (Mb) = 27.4KB -> 5 blocks/CU.
// ---------------------------------------------------------------------------
__global__ __launch_bounds__(256) void attn_kernel(
    const unsigned short* __restrict__ qb, const unsigned short* __restrict__ kb,
    const unsigned short* __restrict__ vb, unsigned short* gob,
    const float* __restrict__ triT, const float* __restrict__ mask)
{
    __shared__ unsigned short Klds[64 * 32];
    __shared__ unsigned short Vt[32 * 68];
    __shared__ unsigned short Plds[4][32 * 68];
    __shared__ float Mb[J_DIM];

    const int t = threadIdx.x;
    const int lane = t & 63, wave = t >> 6;
    const int q15 = lane & 15, quad = lane >> 4;
    const int i = blockIdx.x >> 2, h = blockIdx.x & 3;
    const size_t hb = (size_t)(i * H_DIM + h) * (J_DIM * D_DIM);
    const int m0 = wave * 96;

    for (int idx = t; idx < J_DIM; idx += 256)
        Mb[idx] = 1.0e9f * (mask[i * J_DIM + idx] - 1.0f);

    bf16x8 qf[6];
#pragma unroll
    for (int m = 0; m < 6; ++m)
        qf[m] = *(const bf16x8*)(qb + hb + (size_t)(m0 + m * 16 + q15) * D_DIM + quad * 8);

    f32x4 Oacc[6][2];
    float sums[6][4];
#pragma unroll
    for (int m = 0; m < 6; ++m) {
#pragma unroll
        for (int d2 = 0; d2 < 2; ++d2) Oacc[m][d2] = (f32x4){0.f, 0.f, 0.f, 0.f};
#pragma unroll
        for (int r = 0; r < 4; ++r) sums[m][r] = 0.f;
    }

    unsigned short* Pw = Plds[wave];
    const float* triH = triT + (size_t)h * J_DIM * I_DIM;

    for (int kt = 0; kt < 6; ++kt) {
        __syncthreads();
        {
            const int kp = t >> 2, du = (t & 3) * 8;
            const size_t gsrc = hb + (size_t)(kt * 64 + kp) * D_DIM + du;
            *(int4*)&Klds[kp * 32 + du] = *(const int4*)(kb + gsrc);
            int4 vv = *(const int4*)(vb + gsrc);
            const unsigned short* vs = (const unsigned short*)&vv;
#pragma unroll
            for (int u = 0; u < 8; ++u)
                Vt[(du + u) * 68 + kp] = vs[u];
        }
        __syncthreads();

        // V fragments for this kt (reused by all 3 passes)
        bf16x8 vf[2][2];
#pragma unroll
        for (int ks = 0; ks < 2; ++ks)
#pragma unroll
            for (int d2 = 0; d2 < 2; ++d2)
                vf[ks][d2] = *(const bf16x8*)&Vt[(d2 * 16 + q15) * 68 + ks * 32 + quad * 8];

#pragma unroll
        for (int pass = 0; pass < 3; ++pass) {
            const int mbase = pass * 2;

            // ---- QK^T + exp for 2 m-tiles (nt-outer, kf loaded once/nt) ----
#pragma unroll
            for (int nt = 0; nt < 4; ++nt) {
                const bf16x8 kf = *(const bf16x8*)&Klds[(nt * 16 + q15) * 32 + quad * 8];
                const float mb = Mb[kt * 64 + nt * 16 + q15];
                const float* tcol = triH + (size_t)(kt * 64 + nt * 16 + q15) * I_DIM;
#pragma unroll
                for (int mm = 0; mm < 2; ++mm) {
                    const int m = mbase + mm;
                    const float4 tb = *(const float4*)(tcol + m0 + m * 16 + quad * 4);
                    f32x4 s = {0.f, 0.f, 0.f, 0.f};
                    s = __builtin_amdgcn_mfma_f32_16x16x32_bf16(qf[m], kf, s, 0, 0, 0);
                    const float p0 = __expf(s[0] + mb + tb.x);
                    const float p1 = __expf(s[1] + mb + tb.y);
                    const float p2 = __expf(s[2] + mb + tb.z);
                    const float p3 = __expf(s[3] + mb + tb.w);
                    sums[m][0] += p0; sums[m][1] += p1;
                    sums[m][2] += p2; sums[m][3] += p3;
                    const int row = mm * 16 + quad * 4;
                    const int col = nt * 16 + q15;
                    Pw[(row + 0) * 68 + col] = f2bf(p0);
                    Pw[(row + 1) * 68 + col] = f2bf(p1);
                    Pw[(row + 2) * 68 + col] = f2bf(p2);
                    Pw[(row + 3) * 68 + col] = f2bf(p3);
                }
            }

            // ---- PV for those 2 m-tiles (wave-local P, no barrier needed) ----
#pragma unroll
            for (int mm = 0; mm < 2; ++mm) {
                const int m = mbase + mm;
#pragma unroll
                for (int ks = 0; ks < 2; ++ks) {
                    const bf16x8 af = *(const bf16x8*)&Pw[(mm * 16 + q15) * 68 + ks * 32 + quad * 8];
                    Oacc[m][0] = __builtin_amdgcn_mfma_f32_16x16x32_bf16(af, vf[ks][0], Oacc[m][0], 0, 0, 0);
                    Oacc[m][1] = __builtin_amdgcn_mfma_f32_16x16x32_bf16(af, vf[ks][1], Oacc[m][1], 0, 0, 0);
                }
            }
        }
    }

    float inv[6][4];
#pragma unroll
    for (int m = 0; m < 6; ++m)
#pragma unroll
        for (int r = 0; r < 4; ++r) {
            float s0 = sums[m][r];
            s0 += __shfl_xor(s0, 1); s0 += __shfl_xor(s0, 2);
            s0 += __shfl_xor(s0, 4); s0 += __shfl_xor(s0, 8);
            inv[m][r] = 1.0f / s0;
        }

#pragma unroll
    for (int m = 0; m < 6; ++m) {
        const int qrow = m0 + m * 16 + quad * 4;
#pragma unroll
        for (int d2 = 0; d2 < 2; ++d2) {
            const int d = d2 * 16 + q15;
#pragma unroll
            for (int r = 0; r < 4; ++r) {
                const size_t idx = hb + (size_t)(qrow + r) * D_DIM + d;
                const float g = bf2f(gob[idx]);
                gob[idx] = f2bf(Oacc[m][d2][r] * inv[m][r] * g);
            }
        }
    }
}

// ---------------------------------------------------------------------------
// out: MFMA GEMM.  grid = NPOS/128 = 1152, block = 256.
// ---------------------------------------------------------------------------
__global__ __launch_bounds__(256) void out_kernel(
    const unsigned short* __restrict__ og, const unsigned short* __restrict__ WtO,
    const float* __restrict__ bo, float* __restrict__ out)
{
    __shared__ unsigned short At[128 * 128];
    __shared__ unsigned short Bt[128 * 128];

    const int t = threadIdx.x;
    const int pos0 = blockIdx.x * 128;
    const int lane = t & 63, wave = t >> 6;
    const int q15 = lane & 15, quad = lane >> 4;

    {
        const int r = t >> 1, half = t & 1;
        const int pos = pos0 + r;
        const int i = pos / J_DIM, j = pos - (pos / J_DIM) * J_DIM;
#pragma unroll
        for (int u = 0; u < 8; ++u) {
            const int k0 = half * 64 + u * 8;
            const int hh = k0 >> 5, d0 = k0 & 31;
            const int4 v = *(const int4*)(og + (((size_t)i * H_DIM + hh) * J_DIM + j) * D_DIM + d0);
            const int c = half * 8 + u;
            *(int4*)&At[r * 128 + ((c ^ (r & 7)) * 8)] = v;
        }
        const unsigned short* src = WtO + r * 128 + half * 64;
#pragma unroll
        for (int u = 0; u < 8; ++u) {
            const int c = half * 8 + u;
            *(int4*)&Bt[r * 128 + ((c ^ (r & 7)) * 8)] = *(const int4*)(src + u * 8);
        }
    }
    __syncthreads();

    const int m0 = wave * 32;
    f32x4 acc[2][8];
#pragma unroll
    for (int mt = 0; mt < 2; ++mt)
#pragma unroll
        for (int nt = 0; nt < 8; ++nt) acc[mt][nt] = (f32x4){0.f, 0.f, 0.f, 0.f};

#pragma unroll
    for (int kk = 0; kk < 4; ++kk) {
        const int sw = ((kk * 4 + quad) ^ (q15 & 7)) * 8;
        const bf16x8 a0 = *(const bf16x8*)&At[(m0 + q15) * 128 + sw];
        const bf16x8 a1 = *(const bf16x8*)&At[(m0 + 16 + q15) * 128 + sw];
#pragma unroll
        for (int nt = 0; nt < 8; ++nt) {
            const bf16x8 b = *(const bf16x8*)&Bt[(nt * 16 + q15) * 128 + sw];
            acc[0][nt] = __builtin_amdgcn_mfma_f32_16x16x32_bf16(a0, b, acc[0][nt], 0, 0, 0);
            acc[1][nt] = __builtin_amdgcn_mfma_f32_16x16x32_bf16(a1, b, acc[1][nt], 0, 0, 0);
        }
    }

#pragma unroll
    for (int mt = 0; mt < 2; ++mt)
#pragma unroll
        for (int nt = 0; nt < 8; ++nt) {
            const float bov = bo[nt * 16 + q15];
#pragma unroll
            for (int reg = 0; reg < 4; ++reg) {
                const int pos = pos0 + m0 + mt * 16 + quad * 4 + reg;
                out[(size_t)pos * C_DIM + nt * 16 + q15] = acc[mt][nt][reg] + bov;
            }
        }
}

// ---------------------------------------------------------------------------
extern "C" void kernel_launch(void* const* d_in, const int* in_sizes, int n_in,
                              void* d_out, int out_size, void* d_ws, size_t ws_size,
                              hipStream_t stream)
{
    const float* x     = (const float*)d_in[0];
    const float* mask  = (const float*)d_in[1];
    const float* ln_g  = (const float*)d_in[2];
    const float* ln_b  = (const float*)d_in[3];
    const float* w_tri = (const float*)d_in[4];
    const float* wq    = (const float*)d_in[5];
    const float* wk    = (const float*)d_in[6];
    const float* wv    = (const float*)d_in[7];
    const float* wg    = (const float*)d_in[8];
    const float* bg    = (const float*)d_in[9];
    const float* wo    = (const float*)d_in[10];
    const float* bo    = (const float*)d_in[11];
    float* out = (float*)d_out;
    char* ws = (char*)d_ws;

    const size_t NE = (size_t)NPOS * 128;   // elements per [I,H,J,D] buffer
    unsigned short* qb = (unsigned short*)ws;                     // bf16 36 MiB
    unsigned short* kb = (unsigned short*)(ws + NE * 2);
    unsigned short* vb = (unsigned short*)(ws + NE * 4);
    unsigned short* gb = (unsigned short*)(ws + NE * 6);          // g -> og
    float*         tri = (float*)(ws + NE * 8);                   // [H][J][I]
    unsigned short* Wt = (unsigned short*)(ws + NE * 8 + (size_t)NPOS * 4 * 4);

    prep_kernel<<<5, 256, 0, stream>>>(wq, wk, wv, wg, wo, Wt);
    proj_kernel<<<NPOS / 128, 256, 0, stream>>>(x, ln_g, ln_b, w_tri, Wt, bg,
                                                qb, kb, vb, gb, tri);
    attn_kernel<<<I_DIM * H_DIM, 256, 0, stream>>>(qb, kb, vb, gb, tri, mask);
    out_kernel<<<NPOS / 128, 256, 0, stream>>>(gb, Wt + 4 * 16384, bo, out);
}